// Round 18
// baseline (112.308 us; speedup 1.0000x reference)
//
#include <hip/hip_runtime.h>

typedef _Float16 h2 __attribute__((ext_vector_type(2)));
typedef _Float16 h8 __attribute__((ext_vector_type(8)));
typedef float f32x4 __attribute__((ext_vector_type(4)));

#define B_  16
#define Q_  1024
#define C_  256
#define HW_ 1024
#define TQA 64     // attn queries per block
#define NTA 512
#define QLD 264    // q_lds leading dim (halfwords): 256 + 8 pad
#define BT  256    // conv kernel threads
#define IPB 4      // images per conv block
#define XR  40     // ximg padded row (halfwords)

__device__ __forceinline__ h2 u2h(unsigned u) { return __builtin_bit_cast(h2, u); }
__device__ __forceinline__ unsigned h2u(h2 h) { return __builtin_bit_cast(unsigned, h); }

// packed f16 fma via native v2f16 type (compiler-encoded v_pk_fma_f16)
__device__ __forceinline__ h2 pkfma(h2 a, h2 b, h2 c) {
#if __has_builtin(__builtin_elementwise_fma)
    return __builtin_elementwise_fma(a, b, c);
#else
    return a * b + c;
#endif
}
__device__ __forceinline__ h2 pkmax0(h2 a) {
#if __has_builtin(__builtin_elementwise_max)
    return __builtin_elementwise_max(a, (h2)(_Float16)0.f);
#else
    h2 r;
    r[0] = a[0] > (_Float16)0.f ? a[0] : (_Float16)0.f;
    r[1] = a[1] > (_Float16)0.f ? a[1] : (_Float16)0.f;
    return r;
#endif
}

// ---------- prepass 1: keys f32 -> f16 ----------
__global__ void cvt_keys_f16(const float* __restrict__ src,
                             _Float16* __restrict__ dst, int n8) {
    int i = blockIdx.x * blockDim.x + threadIdx.x;
    if (i >= n8) return;
    const float4* s = (const float4*)src;
    float4 a = s[2 * i], b = s[2 * i + 1];
    h8 v;
    v[0] = (_Float16)a.x; v[1] = (_Float16)a.y; v[2] = (_Float16)a.z; v[3] = (_Float16)a.w;
    v[4] = (_Float16)b.x; v[5] = (_Float16)b.y; v[6] = (_Float16)b.z; v[7] = (_Float16)b.w;
    *(h8*)(dst + (size_t)i * 8) = v;
}

// ---------- prepass 2: pack conv weights ----------
// wpk (u32): [56..91] w2s[t9][c2]=(w2[2c2,t9],w2[2c2+1,t9])   [92] b2 (f32 bits)
//            [96..167]  w1 SPLATS: i=t-96: tap=i>>3, ch=i&7 -> (w1[ch][tap], same)
//            [168..175] b1 splats: (b1[ch], b1[ch])
//            ([0..55] legacy, unused)
__global__ void pack_weights(const float* __restrict__ w1, const float* __restrict__ b1,
                             const float* __restrict__ w2, const float* __restrict__ b2,
                             unsigned* __restrict__ wpk) {
    int t = threadIdx.x;
    if (t < 24) {
        int ch = t / 3, dy = t - ch * 3;
        h2 v = {(_Float16)w1[ch * 9 + dy * 3 + 0], (_Float16)w1[ch * 9 + dy * 3 + 1]};
        wpk[t] = h2u(v);
    } else if (t < 48) {
        int i = t - 24; int ch = i / 3, dy = i - ch * 3;
        h2 v = {(_Float16)w1[ch * 9 + dy * 3 + 2], (_Float16)0.f};
        wpk[t] = h2u(v);
    } else if (t < 56) {
        wpk[t] = __builtin_bit_cast(unsigned, b1[t - 48]);
    } else if (t < 92) {
        int i = t - 56; int t9 = i >> 2, c2 = i & 3;
        h2 v = {(_Float16)w2[(2 * c2) * 9 + t9], (_Float16)w2[(2 * c2 + 1) * 9 + t9]};
        wpk[t] = h2u(v);
    } else if (t == 92) {
        wpk[t] = __builtin_bit_cast(unsigned, b2[0]);
    } else if (t >= 96 && t < 168) {
        int i = t - 96; int tap = i >> 3, ch = i & 7;
        _Float16 w = (_Float16)w1[ch * 9 + tap];
        h2 v = {w, w};
        wpk[t] = h2u(v);
    } else if (t >= 168 && t < 176) {
        _Float16 b = (_Float16)b1[t - 168];
        h2 v = {b, b};
        wpk[t] = h2u(v);
    }
}

// ---------- kernel A: QK^T (f16 MFMA, TQ=64, 4 MFMA per B-load) + bias + softmax ----------
__global__ __launch_bounds__(NTA, 2) void attn_kernel(
    const float* __restrict__ queries, const _Float16* __restrict__ keysh,
    const int* __restrict__ pos, const float* __restrict__ rel_bias,
    _Float16* __restrict__ xmapg)
{
    __shared__ _Float16 q_lds[TQA * QLD];      // 33.8 KiB
    __shared__ _Float16 bias_lds[63 * 64];     // 8 KiB
    __shared__ float red_max[8][TQA];
    __shared__ float red_sum[8][TQA];
    __shared__ int2  pos_lds[TQA];

    const int tid = threadIdx.x;
    const int bid = blockIdx.x;
    const int swz = (bid & 7) * 32 + (bid >> 3);    // XCD-chunked (256 % 8 == 0)
    const int batch = swz >> 4;
    const int tile  = swz & 15;

    {
        const float4* qsrc = (const float4*)(queries + (size_t)(batch * Q_ + tile * TQA) * C_);
        #pragma unroll
        for (int i = 0; i < 8; ++i) {
            int e4 = i * NTA + tid;                 // 0..4095
            float4 v = qsrc[e4];
            int row = e4 >> 6, col4 = e4 & 63;
            _Float16* d = &q_lds[row * QLD + col4 * 4];
            d[0] = (_Float16)v.x; d[1] = (_Float16)v.y;
            d[2] = (_Float16)v.z; d[3] = (_Float16)v.w;
        }
        for (int idx = tid; idx < 63 * 63; idx += NTA) {
            int r = idx / 63;
            bias_lds[r * 64 + (idx - r * 63)] = (_Float16)rel_bias[idx];
        }
        if (tid < TQA)
            pos_lds[tid] = ((const int2*)pos)[batch * Q_ + tile * TQA + tid];
    }
    __syncthreads();

    const int lane = tid & 63;
    const int wv   = tid >> 6;          // 0..7 -> 128-col slice
    const int kgrp = (lane >> 4) * 8;
    const int l15  = lane & 15;
    const int rowbase = (lane >> 4) << 2;

    f32x4 acc[4][8];
    #pragma unroll
    for (int mt = 0; mt < 4; ++mt)
        #pragma unroll
        for (int f = 0; f < 8; ++f) acc[mt][f] = f32x4{0.f, 0.f, 0.f, 0.f};

    const _Float16* kb = keysh + (size_t)batch * (HW_ * C_)
                       + (size_t)(wv * 128 + l15) * C_ + kgrp;
    #pragma unroll
    for (int ks = 0; ks < 8; ++ks) {
        h8 a[4];
        #pragma unroll
        for (int mt = 0; mt < 4; ++mt)
            a[mt] = *(const h8*)&q_lds[(mt * 16 + l15) * QLD + ks * 32 + kgrp];
        #pragma unroll
        for (int f = 0; f < 8; ++f) {
            h8 bfr = *(const h8*)(kb + f * (16 * C_) + ks * 32);
            #pragma unroll
            for (int mt = 0; mt < 4; ++mt)
                acc[mt][f] = __builtin_amdgcn_mfma_f32_16x16x32_f16(a[mt], bfr, acc[mt][f], 0, 0, 0);
        }
    }
    // C/D: col = wv*128 + f*16 + l15, row = mt*16 + rowbase + r

    int p0r[4][4], p1r[4][4];
    #pragma unroll
    for (int mt = 0; mt < 4; ++mt)
        #pragma unroll
        for (int r = 0; r < 4; ++r) {
            int2 pp = pos_lds[mt * 16 + rowbase + r];
            p0r[mt][r] = pp.x; p1r[mt][r] = pp.y;
        }

    float mrow[4][4];
    #pragma unroll
    for (int mt = 0; mt < 4; ++mt)
        #pragma unroll
        for (int r = 0; r < 4; ++r) mrow[mt][r] = -3e38f;

    #pragma unroll
    for (int f = 0; f < 8; ++f) {
        int col = wv * 128 + f * 16 + l15;
        int hh = col >> 5, ww = col & 31;
        #pragma unroll
        for (int mt = 0; mt < 4; ++mt)
            #pragma unroll
            for (int r = 0; r < 4; ++r) {
                float s = acc[mt][f][r] * 0.0625f
                        + (float)bias_lds[(hh - p0r[mt][r] + 31) * 64 + (ww - p1r[mt][r] + 31)];
                acc[mt][f][r] = s;
                mrow[mt][r] = fmaxf(mrow[mt][r], s);
            }
    }
    #pragma unroll
    for (int mt = 0; mt < 4; ++mt)
        #pragma unroll
        for (int r = 0; r < 4; ++r) {
            float m = mrow[mt][r];
            m = fmaxf(m, __shfl_xor(m, 1, 64));
            m = fmaxf(m, __shfl_xor(m, 2, 64));
            m = fmaxf(m, __shfl_xor(m, 4, 64));
            m = fmaxf(m, __shfl_xor(m, 8, 64));
            mrow[mt][r] = m;
        }
    if (l15 == 0) {
        #pragma unroll
        for (int mt = 0; mt < 4; ++mt)
            #pragma unroll
            for (int r = 0; r < 4; ++r)
                red_max[wv][mt * 16 + rowbase + r] = mrow[mt][r];
    }
    __syncthreads();

    float sm[4][4];
    #pragma unroll
    for (int mt = 0; mt < 4; ++mt)
        #pragma unroll
        for (int r = 0; r < 4; ++r) {
            float m = red_max[0][mt * 16 + rowbase + r];
            #pragma unroll
            for (int w = 1; w < 8; ++w) m = fmaxf(m, red_max[w][mt * 16 + rowbase + r]);
            mrow[mt][r] = m;     // reuse as row max
            sm[mt][r] = 0.f;
        }

    #pragma unroll
    for (int f = 0; f < 8; ++f) {
        #pragma unroll
        for (int mt = 0; mt < 4; ++mt)
            #pragma unroll
            for (int r = 0; r < 4; ++r) {
                float e = __expf(acc[mt][f][r] - mrow[mt][r]);
                acc[mt][f][r] = e;
                sm[mt][r] += e;
            }
    }
    #pragma unroll
    for (int mt = 0; mt < 4; ++mt)
        #pragma unroll
        for (int r = 0; r < 4; ++r) {
            float s = sm[mt][r];
            s += __shfl_xor(s, 1, 64);
            s += __shfl_xor(s, 2, 64);
            s += __shfl_xor(s, 4, 64);
            s += __shfl_xor(s, 8, 64);
            sm[mt][r] = s;
        }
    if (l15 == 0) {
        #pragma unroll
        for (int mt = 0; mt < 4; ++mt)
            #pragma unroll
            for (int r = 0; r < 4; ++r)
                red_sum[wv][mt * 16 + rowbase + r] = sm[mt][r];
    }
    __syncthreads();

    _Float16* xg = xmapg + (size_t)(batch * Q_ + tile * TQA) * HW_;
    #pragma unroll
    for (int mt = 0; mt < 4; ++mt) {
        float sinv[4];
        #pragma unroll
        for (int r = 0; r < 4; ++r) {
            float S = red_sum[0][mt * 16 + rowbase + r];
            #pragma unroll
            for (int w = 1; w < 8; ++w) S += red_sum[w][mt * 16 + rowbase + r];
            sinv[r] = 1.0f / S;
        }
        #pragma unroll
        for (int f = 0; f < 8; ++f) {
            int col = wv * 128 + f * 16 + l15;
            #pragma unroll
            for (int r = 0; r < 4; ++r)
                xg[(size_t)(mt * 16 + rowbase + r) * HW_ + col]
                    = (_Float16)(acc[mt][f][r] * sinv[r]);
        }
    }
}

// ---------- kernel B: conv1 + conv2 both packed f16 (px-pair / ch-pair) ----------
// R17 structure; conv2 MAC body now packed f16 ch-pair accumulation.
__global__ __launch_bounds__(BT, 4) void conv_kernel(
    const _Float16* __restrict__ xmapg, const unsigned* __restrict__ wpk,
    float* __restrict__ out)
{
    __shared__ _Float16 ximg[IPB][32 * XR];          // 10240 B
    __shared__ __align__(16) char Hb[16384];         // 1 image H (permuted cols)
    __shared__ unsigned wsh[176];                    // weights (LDS-resident)

    const int tid = threadIdx.x;
    const int bid = blockIdx.x;
    const int swz = (bid & 7) * 512 + (bid >> 3);    // XCD-chunked (4096 % 8 == 0)
    const size_t img0 = (size_t)swz * IPB;

    // ---- stage weights + 4 images ----
    if (tid < 176) wsh[tid] = wpk[tid];
    #pragma unroll
    for (int i = 0; i < 2; ++i) {
        int c = i * BT + tid;            // 0..511 : 16B chunks
        int im = c >> 7, cc = c & 127;
        uint4 v = *(const uint4*)(xmapg + img0 * HW_ + (size_t)im * HW_ + cc * 8);
        *(uint4*)&ximg[im][(cc >> 2) * XR + (cc & 3) * 8] = v;
    }
    __syncthreads();

    // thread -> (y, 4-px x-run)
    const int x0 = (tid & 7) << 2;
    const int y  = tid >> 3;

    #pragma unroll 1
    for (int img = 0; img < IPB; ++img) {
        const _Float16* xim = &ximg[img][0];

        // --- gather shift-pair words (guarded; proven) ---
        unsigned Pm[3], A0[3], Pc[3], A1[3], Pe[3];
        #pragma unroll
        for (int dy = 0; dy < 3; ++dy) {
            int yy = y + dy - 1;
            unsigned b0 = 0, b1v = 0, em = 0, e4 = 0;
            if ((unsigned)yy < 32u) {
                const _Float16* row = xim + yy * XR + x0;
                uint2 bb = *(const uint2*)row;        // (v0,v1 | v2,v3)
                b0 = bb.x; b1v = bb.y;
                if (x0 > 0)      em = *(const unsigned short*)(row - 1);  // v-1
                if (x0 + 4 < 32) e4 = *(const unsigned short*)(row + 4);  // v4
            }
            Pm[dy] = (em & 0xffffu) | (b0 << 16);    // (v-1, v0)
            A0[dy] = b0;                             // (v0, v1)
            Pc[dy] = (b0 >> 16) | (b1v << 16);       // (v1, v2)
            A1[dy] = b1v;                            // (v2, v3)
            Pe[dy] = (b1v >> 16) | (e4 << 16);       // (v3, v4)
        }

        // --- conv1: packed-f16 px-pair accumulation (R17-proven) ---
        unsigned hvw[4][4];   // [px][chpair word]
        #pragma unroll
        for (int p2 = 0; p2 < 2; ++p2) {
            h2 accp[8];
            #pragma unroll
            for (int ch = 0; ch < 8; ++ch)
                accp[ch] = u2h(wsh[168 + ch]);       // b1 splat
            #pragma unroll
            for (int dy = 0; dy < 3; ++dy) {
                const unsigned W0 = p2 ? Pc[dy] : Pm[dy];
                const unsigned W1 = p2 ? A1[dy] : A0[dy];
                const unsigned W2 = p2 ? Pe[dy] : Pc[dy];
                #pragma unroll
                for (int ch = 0; ch < 8; ++ch) {
                    accp[ch] = pkfma(u2h(W0), u2h(wsh[96 + (dy * 3 + 0) * 8 + ch]), accp[ch]);
                    accp[ch] = pkfma(u2h(W1), u2h(wsh[96 + (dy * 3 + 1) * 8 + ch]), accp[ch]);
                    accp[ch] = pkfma(u2h(W2), u2h(wsh[96 + (dy * 3 + 2) * 8 + ch]), accp[ch]);
                }
            }
            #pragma unroll
            for (int w = 0; w < 4; ++w) {
                unsigned a = h2u(pkmax0(accp[2 * w]));
                unsigned b = h2u(pkmax0(accp[2 * w + 1]));
                hvw[2 * p2 + 0][w] = (a & 0xffffu) | (b << 16);
                hvw[2 * p2 + 1][w] = (a >> 16) | (b & 0xffff0000u);
            }
        }

        __syncthreads();   // previous image's conv2 readers done with Hb

        // store channel-pairs (slot permutation: px c -> (c&3)*8 + (c>>2))
        {
            char* wbp = Hb + (y << 9);
            const int m4 = x0 >> 2;
            #pragma unroll
            for (int j = 0; j < 4; ++j) {
                uint4 hv = {hvw[j][0], hvw[j][1], hvw[j][2], hvw[j][3]};
                *(uint4*)(wbp + ((j * 8 + m4) << 4)) = hv;
            }
        }
        __syncthreads();   // Hb ready

        // --- conv2: packed-f16 ch-pair accumulation + residual -> out ---
        h2 a2p[4];
        #pragma unroll
        for (int j = 0; j < 4; ++j) a2p[j] = u2h(0u);
        #pragma unroll
        for (int dy = 0; dy < 3; ++dy) {
            int yy = y + dy - 1;
            uint4 Hv[6];
            if ((unsigned)yy < 32u) {
                const char* rb = Hb + (yy << 9);
                #pragma unroll
                for (int k = 0; k < 6; ++k) {
                    int c = x0 - 1 + k;
                    if ((unsigned)c < 32u) {
                        unsigned g = (((unsigned)(c & 3)) << 3) | ((unsigned)c >> 2);
                        Hv[k] = *(const uint4*)(rb + (g << 4));
                    } else
                        Hv[k] = uint4{0u, 0u, 0u, 0u};
                }
            } else {
                #pragma unroll
                for (int k = 0; k < 6; ++k) Hv[k] = uint4{0u, 0u, 0u, 0u};
            }
            #pragma unroll
            for (int dx = 0; dx < 3; ++dx) {
                const int tt = dy * 3 + dx;
                const h2 w0 = u2h(wsh[56 + tt * 4 + 0]);
                const h2 w1 = u2h(wsh[56 + tt * 4 + 1]);
                const h2 w2 = u2h(wsh[56 + tt * 4 + 2]);
                const h2 w3 = u2h(wsh[56 + tt * 4 + 3]);
                #pragma unroll
                for (int j = 0; j < 4; ++j) {
                    const uint4 uu = Hv[j + dx];
                    a2p[j] = pkfma(u2h(uu.x), w0, a2p[j]);
                    a2p[j] = pkfma(u2h(uu.y), w1, a2p[j]);
                    a2p[j] = pkfma(u2h(uu.z), w2, a2p[j]);
                    a2p[j] = pkfma(u2h(uu.w), w3, a2p[j]);
                }
            }
        }
        {
            const float b2r = __builtin_bit_cast(float, wsh[92]);
            const _Float16* xr4 = xim + y * XR + x0;
            uint2 rr = *(const uint2*)xr4;
            h2 lo = u2h(rr.x), hi = u2h(rr.y);
            float4 o;
            o.x = (float)lo[0] + (float)a2p[0][0] + (float)a2p[0][1] + b2r;
            o.y = (float)lo[1] + (float)a2p[1][0] + (float)a2p[1][1] + b2r;
            o.z = (float)hi[0] + (float)a2p[2][0] + (float)a2p[2][1] + b2r;
            o.w = (float)hi[1] + (float)a2p[3][0] + (float)a2p[3][1] + b2r;
            *(float4*)(out + (img0 + img) * HW_ + y * 32 + x0) = o;
        }
    }
}

extern "C" void kernel_launch(void* const* d_in, const int* in_sizes, int n_in,
                              void* d_out, int out_size, void* d_ws, size_t ws_size,
                              hipStream_t stream) {
    const float* queries  = (const float*)d_in[0];
    const float* keys     = (const float*)d_in[1];
    const int*   pos      = (const int*)d_in[2];
    const float* rel_bias = (const float*)d_in[3];
    const float* w1       = (const float*)d_in[4];
    const float* b1       = (const float*)d_in[5];
    const float* w2       = (const float*)d_in[6];
    const float* b2       = (const float*)d_in[7];
    float* out = (float*)d_out;

    unsigned*  wpk   = (unsigned*)d_ws;                                  // 4 KiB slot
    _Float16*  keysh = (_Float16*)((char*)d_ws + 4096);                  // 8 MiB
    _Float16*  xmapg = (_Float16*)((char*)d_ws + 4096 + 8388608);        // 32 MiB

    const int n8 = (B_ * HW_ * C_) / 8;  // 524288
    pack_weights<<<dim3(1), dim3(192), 0, stream>>>(w1, b1, w2, b2, wpk);
    cvt_keys_f16<<<dim3(n8 / 256), dim3(256), 0, stream>>>(keys, keysh, n8);
    attn_kernel<<<dim3(B_ * (Q_ / TQA)), dim3(NTA), 0, stream>>>(
        queries, keysh, pos, rel_bias, xmapg);
    conv_kernel<<<dim3((B_ * Q_) / IPB), dim3(BT), 0, stream>>>(xmapg, wpk, out);
}

// Round 19
// 108.701 us; speedup vs baseline: 1.0332x; 1.0332x over previous
//
#include <hip/hip_runtime.h>

typedef _Float16 h2 __attribute__((ext_vector_type(2)));
typedef _Float16 h8 __attribute__((ext_vector_type(8)));
typedef float f32x4 __attribute__((ext_vector_type(4)));

#define B_  16
#define Q_  1024
#define C_  256
#define HW_ 1024
#define TQA 64     // attn queries per block
#define NTA 512
#define QLD 264    // q_lds leading dim (halfwords): 256 + 8 pad
#define BT  256    // conv kernel threads
#define IPB 4      // images per conv block
#define XRB 80     // bytes per padded ximg row (40 halfwords: 32 px + 8 zero pad)
#define XIMGB (34 * XRB)   // 2720 B per padded image (34 rows, zero top/bottom)
#define HRB 576    // bytes per Hb row (36 slots * 16B, zero border)

__device__ __forceinline__ h2 u2h(unsigned u) { return __builtin_bit_cast(h2, u); }
__device__ __forceinline__ unsigned h2u(h2 h) { return __builtin_bit_cast(unsigned, h); }

// packed f16 fma via native v2f16 type (compiler-encoded v_pk_fma_f16)
__device__ __forceinline__ h2 pkfma(h2 a, h2 b, h2 c) {
#if __has_builtin(__builtin_elementwise_fma)
    return __builtin_elementwise_fma(a, b, c);
#else
    return a * b + c;
#endif
}
__device__ __forceinline__ h2 pkmax0(h2 a) {
#if __has_builtin(__builtin_elementwise_max)
    return __builtin_elementwise_max(a, (h2)(_Float16)0.f);
#else
    h2 r;
    r[0] = a[0] > (_Float16)0.f ? a[0] : (_Float16)0.f;
    r[1] = a[1] > (_Float16)0.f ? a[1] : (_Float16)0.f;
    return r;
#endif
}

// ---------- prepass 1: keys f32 -> f16 ----------
__global__ void cvt_keys_f16(const float* __restrict__ src,
                             _Float16* __restrict__ dst, int n8) {
    int i = blockIdx.x * blockDim.x + threadIdx.x;
    if (i >= n8) return;
    const float4* s = (const float4*)src;
    float4 a = s[2 * i], b = s[2 * i + 1];
    h8 v;
    v[0] = (_Float16)a.x; v[1] = (_Float16)a.y; v[2] = (_Float16)a.z; v[3] = (_Float16)a.w;
    v[4] = (_Float16)b.x; v[5] = (_Float16)b.y; v[6] = (_Float16)b.z; v[7] = (_Float16)b.w;
    *(h8*)(dst + (size_t)i * 8) = v;
}

// ---------- prepass 2: pack conv weights ----------
// wpk (u32): [56..91] w2s[t9][c2]=(w2[2c2,t9],w2[2c2+1,t9])   [92] b2 (f32 bits)
//            [96..167]  w1 SPLATS: i=t-96: tap=i>>3, ch=i&7 -> (w1[ch][tap], same)
//            [168..175] b1 splats: (b1[ch], b1[ch])
__global__ void pack_weights(const float* __restrict__ w1, const float* __restrict__ b1,
                             const float* __restrict__ w2, const float* __restrict__ b2,
                             unsigned* __restrict__ wpk) {
    int t = threadIdx.x;
    if (t < 24) {
        int ch = t / 3, dy = t - ch * 3;
        h2 v = {(_Float16)w1[ch * 9 + dy * 3 + 0], (_Float16)w1[ch * 9 + dy * 3 + 1]};
        wpk[t] = h2u(v);
    } else if (t < 48) {
        int i = t - 24; int ch = i / 3, dy = i - ch * 3;
        h2 v = {(_Float16)w1[ch * 9 + dy * 3 + 2], (_Float16)0.f};
        wpk[t] = h2u(v);
    } else if (t < 56) {
        wpk[t] = __builtin_bit_cast(unsigned, b1[t - 48]);
    } else if (t < 92) {
        int i = t - 56; int t9 = i >> 2, c2 = i & 3;
        h2 v = {(_Float16)w2[(2 * c2) * 9 + t9], (_Float16)w2[(2 * c2 + 1) * 9 + t9]};
        wpk[t] = h2u(v);
    } else if (t == 92) {
        wpk[t] = __builtin_bit_cast(unsigned, b2[0]);
    } else if (t >= 96 && t < 168) {
        int i = t - 96; int tap = i >> 3, ch = i & 7;
        _Float16 w = (_Float16)w1[ch * 9 + tap];
        h2 v = {w, w};
        wpk[t] = h2u(v);
    } else if (t >= 168 && t < 176) {
        _Float16 b = (_Float16)b1[t - 168];
        h2 v = {b, b};
        wpk[t] = h2u(v);
    }
}

// ---------- kernel A: QK^T (f16 MFMA, TQ=64, 4 MFMA per B-load) + bias + softmax ----------
__global__ __launch_bounds__(NTA, 2) void attn_kernel(
    const float* __restrict__ queries, const _Float16* __restrict__ keysh,
    const int* __restrict__ pos, const float* __restrict__ rel_bias,
    _Float16* __restrict__ xmapg)
{
    __shared__ _Float16 q_lds[TQA * QLD];      // 33.8 KiB
    __shared__ _Float16 bias_lds[63 * 64];     // 8 KiB
    __shared__ float red_max[8][TQA];
    __shared__ float red_sum[8][TQA];
    __shared__ int2  pos_lds[TQA];

    const int tid = threadIdx.x;
    const int bid = blockIdx.x;
    const int swz = (bid & 7) * 32 + (bid >> 3);    // XCD-chunked (256 % 8 == 0)
    const int batch = swz >> 4;
    const int tile  = swz & 15;

    {
        const float4* qsrc = (const float4*)(queries + (size_t)(batch * Q_ + tile * TQA) * C_);
        #pragma unroll
        for (int i = 0; i < 8; ++i) {
            int e4 = i * NTA + tid;                 // 0..4095
            float4 v = qsrc[e4];
            int row = e4 >> 6, col4 = e4 & 63;
            _Float16* d = &q_lds[row * QLD + col4 * 4];
            d[0] = (_Float16)v.x; d[1] = (_Float16)v.y;
            d[2] = (_Float16)v.z; d[3] = (_Float16)v.w;
        }
        for (int idx = tid; idx < 63 * 63; idx += NTA) {
            int r = idx / 63;
            bias_lds[r * 64 + (idx - r * 63)] = (_Float16)rel_bias[idx];
        }
        if (tid < TQA)
            pos_lds[tid] = ((const int2*)pos)[batch * Q_ + tile * TQA + tid];
    }
    __syncthreads();

    const int lane = tid & 63;
    const int wv   = tid >> 6;          // 0..7 -> 128-col slice
    const int kgrp = (lane >> 4) * 8;
    const int l15  = lane & 15;
    const int rowbase = (lane >> 4) << 2;

    f32x4 acc[4][8];
    #pragma unroll
    for (int mt = 0; mt < 4; ++mt)
        #pragma unroll
        for (int f = 0; f < 8; ++f) acc[mt][f] = f32x4{0.f, 0.f, 0.f, 0.f};

    const _Float16* kb = keysh + (size_t)batch * (HW_ * C_)
                       + (size_t)(wv * 128 + l15) * C_ + kgrp;
    #pragma unroll
    for (int ks = 0; ks < 8; ++ks) {
        h8 a[4];
        #pragma unroll
        for (int mt = 0; mt < 4; ++mt)
            a[mt] = *(const h8*)&q_lds[(mt * 16 + l15) * QLD + ks * 32 + kgrp];
        #pragma unroll
        for (int f = 0; f < 8; ++f) {
            h8 bfr = *(const h8*)(kb + f * (16 * C_) + ks * 32);
            #pragma unroll
            for (int mt = 0; mt < 4; ++mt)
                acc[mt][f] = __builtin_amdgcn_mfma_f32_16x16x32_f16(a[mt], bfr, acc[mt][f], 0, 0, 0);
        }
    }
    // C/D: col = wv*128 + f*16 + l15, row = mt*16 + rowbase + r

    int p0r[4][4], p1r[4][4];
    #pragma unroll
    for (int mt = 0; mt < 4; ++mt)
        #pragma unroll
        for (int r = 0; r < 4; ++r) {
            int2 pp = pos_lds[mt * 16 + rowbase + r];
            p0r[mt][r] = pp.x; p1r[mt][r] = pp.y;
        }

    float mrow[4][4];
    #pragma unroll
    for (int mt = 0; mt < 4; ++mt)
        #pragma unroll
        for (int r = 0; r < 4; ++r) mrow[mt][r] = -3e38f;

    #pragma unroll
    for (int f = 0; f < 8; ++f) {
        int col = wv * 128 + f * 16 + l15;
        int hh = col >> 5, ww = col & 31;
        #pragma unroll
        for (int mt = 0; mt < 4; ++mt)
            #pragma unroll
            for (int r = 0; r < 4; ++r) {
                float s = acc[mt][f][r] * 0.0625f
                        + (float)bias_lds[(hh - p0r[mt][r] + 31) * 64 + (ww - p1r[mt][r] + 31)];
                acc[mt][f][r] = s;
                mrow[mt][r] = fmaxf(mrow[mt][r], s);
            }
    }
    #pragma unroll
    for (int mt = 0; mt < 4; ++mt)
        #pragma unroll
        for (int r = 0; r < 4; ++r) {
            float m = mrow[mt][r];
            m = fmaxf(m, __shfl_xor(m, 1, 64));
            m = fmaxf(m, __shfl_xor(m, 2, 64));
            m = fmaxf(m, __shfl_xor(m, 4, 64));
            m = fmaxf(m, __shfl_xor(m, 8, 64));
            mrow[mt][r] = m;
        }
    if (l15 == 0) {
        #pragma unroll
        for (int mt = 0; mt < 4; ++mt)
            #pragma unroll
            for (int r = 0; r < 4; ++r)
                red_max[wv][mt * 16 + rowbase + r] = mrow[mt][r];
    }
    __syncthreads();

    float sm[4][4];
    #pragma unroll
    for (int mt = 0; mt < 4; ++mt)
        #pragma unroll
        for (int r = 0; r < 4; ++r) {
            float m = red_max[0][mt * 16 + rowbase + r];
            #pragma unroll
            for (int w = 1; w < 8; ++w) m = fmaxf(m, red_max[w][mt * 16 + rowbase + r]);
            mrow[mt][r] = m;     // reuse as row max
            sm[mt][r] = 0.f;
        }

    #pragma unroll
    for (int f = 0; f < 8; ++f) {
        #pragma unroll
        for (int mt = 0; mt < 4; ++mt)
            #pragma unroll
            for (int r = 0; r < 4; ++r) {
                float e = __expf(acc[mt][f][r] - mrow[mt][r]);
                acc[mt][f][r] = e;
                sm[mt][r] += e;
            }
    }
    #pragma unroll
    for (int mt = 0; mt < 4; ++mt)
        #pragma unroll
        for (int r = 0; r < 4; ++r) {
            float s = sm[mt][r];
            s += __shfl_xor(s, 1, 64);
            s += __shfl_xor(s, 2, 64);
            s += __shfl_xor(s, 4, 64);
            s += __shfl_xor(s, 8, 64);
            sm[mt][r] = s;
        }
    if (l15 == 0) {
        #pragma unroll
        for (int mt = 0; mt < 4; ++mt)
            #pragma unroll
            for (int r = 0; r < 4; ++r)
                red_sum[wv][mt * 16 + rowbase + r] = sm[mt][r];
    }
    __syncthreads();

    _Float16* xg = xmapg + (size_t)(batch * Q_ + tile * TQA) * HW_;
    #pragma unroll
    for (int mt = 0; mt < 4; ++mt) {
        float sinv[4];
        #pragma unroll
        for (int r = 0; r < 4; ++r) {
            float S = red_sum[0][mt * 16 + rowbase + r];
            #pragma unroll
            for (int w = 1; w < 8; ++w) S += red_sum[w][mt * 16 + rowbase + r];
            sinv[r] = 1.0f / S;
        }
        #pragma unroll
        for (int f = 0; f < 8; ++f) {
            int col = wv * 128 + f * 16 + l15;
            #pragma unroll
            for (int r = 0; r < 4; ++r)
                xg[(size_t)(mt * 16 + rowbase + r) * HW_ + col]
                    = (_Float16)(acc[mt][f][r] * sinv[r]);
        }
    }
}

// ---------- kernel B: conv1+conv2 packed f16, guard-free padded layouts ----------
// MAC bodies = R17/R18 (proven); addressing = R14's padded xall + bordered Hb
// (proven); weights LDS-use-site (anti-spill).
__global__ __launch_bounds__(BT, 4) void conv_kernel(
    const _Float16* __restrict__ xmapg, const unsigned* __restrict__ wpk,
    float* __restrict__ out)
{
    __shared__ __align__(16) char xall[16 + IPB * XIMGB];   // 10896 B
    __shared__ __align__(16) char Hb[34 * HRB];             // 19584 B
    __shared__ unsigned wsh[176];                           // 704 B

    const int tid = threadIdx.x;
    const int bid = blockIdx.x;
    const int swz = (bid & 7) * 512 + (bid >> 3);    // XCD-chunked (4096 % 8 == 0)
    const size_t img0 = (size_t)swz * IPB;

    // ---- zero-fill pads/borders; barrier BEFORE interior staging ----
    {
        const uint4 z = uint4{0u, 0u, 0u, 0u};
        uint4* xz = (uint4*)xall;
        for (int i = tid; i < (int)sizeof(xall) / 16; i += BT) xz[i] = z;
        uint4* hz = (uint4*)Hb;
        for (int i = tid; i < (int)sizeof(Hb) / 16; i += BT) hz[i] = z;
    }
    if (tid < 176) wsh[tid] = wpk[tid];
    __syncthreads();

    // ---- stage 4 images (rows at r+1, cols 0..31 of 40) ----
    #pragma unroll
    for (int i = 0; i < 2; ++i) {
        int c = i * BT + tid;            // 0..511 : 16B chunks
        int im = c >> 7, cc = c & 127, r = cc >> 2, q = cc & 3;
        uint4 v = *(const uint4*)(xmapg + img0 * HW_ + (size_t)im * HW_ + cc * 8);
        *(uint4*)(xall + 16 + im * XIMGB + (r + 1) * XRB + q * 16) = v;
    }

    // thread -> (y, 4-px x-run)
    const int m4 = tid & 7;
    const int y  = tid >> 3;
    const int x0 = m4 << 2;

    // window rows for output row y: padded rows y, y+1, y+2 (image rows y-1..y+1)
    const char* const xrow0 = xall + 16 + y * XRB + x0 * 2;
    char* const hwr = Hb + (y + 1) * HRB + m4 * 16;         // conv1 store base
    const char* const hrd = Hb + y * HRB + m4 * 16;         // conv2 read base

    __syncthreads();   // staging complete

    #pragma unroll 1
    for (int img = 0; img < IPB; ++img) {
        const char* xi = xrow0 + img * XIMGB;

        // --- gather: 9 unguarded loads + 3 alignbit per row (zero pads guard) ---
        unsigned Pm[3], A0[3], Pc[3], A1[3], Pe[3];
        #pragma unroll
        for (int dy = 0; dy < 3; ++dy) {
            unsigned em = *(const unsigned*)(xi + dy * XRB - 4);   // (v-2, v-1)
            uint2 a01   = *(const uint2*)(xi + dy * XRB);          // v0..v3
            unsigned e4 = *(const unsigned*)(xi + dy * XRB + 8);   // (v4, v5)
            A0[dy] = a01.x; A1[dy] = a01.y;
            Pm[dy] = __builtin_amdgcn_alignbit(a01.x, em, 16);     // (v-1, v0)
            Pc[dy] = __builtin_amdgcn_alignbit(a01.y, a01.x, 16);  // (v1, v2)
            Pe[dy] = __builtin_amdgcn_alignbit(e4, a01.y, 16);     // (v3, v4)
        }

        // --- conv1: packed-f16 px-pair accumulation (R17-proven) ---
        unsigned hvw[4][4];   // [px][chpair word]
        #pragma unroll
        for (int p2 = 0; p2 < 2; ++p2) {
            h2 accp[8];
            #pragma unroll
            for (int ch = 0; ch < 8; ++ch)
                accp[ch] = u2h(wsh[168 + ch]);       // b1 splat
            #pragma unroll
            for (int dy = 0; dy < 3; ++dy) {
                const unsigned W0 = p2 ? Pc[dy] : Pm[dy];
                const unsigned W1 = p2 ? A1[dy] : A0[dy];
                const unsigned W2 = p2 ? Pe[dy] : Pc[dy];
                #pragma unroll
                for (int ch = 0; ch < 8; ++ch) {
                    accp[ch] = pkfma(u2h(W0), u2h(wsh[96 + (dy * 3 + 0) * 8 + ch]), accp[ch]);
                    accp[ch] = pkfma(u2h(W1), u2h(wsh[96 + (dy * 3 + 1) * 8 + ch]), accp[ch]);
                    accp[ch] = pkfma(u2h(W2), u2h(wsh[96 + (dy * 3 + 2) * 8 + ch]), accp[ch]);
                }
            }
            #pragma unroll
            for (int w = 0; w < 4; ++w) {
                unsigned a = h2u(pkmax0(accp[2 * w]));
                unsigned b = h2u(pkmax0(accp[2 * w + 1]));
                hvw[2 * p2 + 0][w] = (a & 0xffffu) | (b << 16);
                hvw[2 * p2 + 1][w] = (a >> 16) | (b & 0xffff0000u);
            }
        }

        __syncthreads();   // previous image's conv2 readers done with Hb

        // store (bordered slots, R14-proven: cp=x0+j+1 -> (cp&3)*9+(cp>>2))
        {
            *(uint4*)(hwr + 144) = uint4{hvw[0][0], hvw[0][1], hvw[0][2], hvw[0][3]};
            *(uint4*)(hwr + 288) = uint4{hvw[1][0], hvw[1][1], hvw[1][2], hvw[1][3]};
            *(uint4*)(hwr + 432) = uint4{hvw[2][0], hvw[2][1], hvw[2][2], hvw[2][3]};
            *(uint4*)(hwr + 16)  = uint4{hvw[3][0], hvw[3][1], hvw[3][2], hvw[3][3]};
        }
        __syncthreads();   // Hb ready

        // --- conv2: packed-f16 ch-pair accum, unguarded reads (zero border) ---
        h2 a2p[4];
        #pragma unroll
        for (int j = 0; j < 4; ++j) a2p[j] = u2h(0u);
        #pragma unroll
        for (int dy = 0; dy < 3; ++dy) {
            const char* rb = hrd + dy * HRB;
            uint4 Hv[6];
            Hv[0] = *(const uint4*)(rb + 0);     // c = x0-1
            Hv[1] = *(const uint4*)(rb + 144);   // c = x0
            Hv[2] = *(const uint4*)(rb + 288);   // c = x0+1
            Hv[3] = *(const uint4*)(rb + 432);   // c = x0+2
            Hv[4] = *(const uint4*)(rb + 16);    // c = x0+3
            Hv[5] = *(const uint4*)(rb + 160);   // c = x0+4
            #pragma unroll
            for (int dx = 0; dx < 3; ++dx) {
                const int tt = dy * 3 + dx;
                const h2 w0 = u2h(wsh[56 + tt * 4 + 0]);
                const h2 w1 = u2h(wsh[56 + tt * 4 + 1]);
                const h2 w2 = u2h(wsh[56 + tt * 4 + 2]);
                const h2 w3 = u2h(wsh[56 + tt * 4 + 3]);
                #pragma unroll
                for (int j = 0; j < 4; ++j) {
                    const uint4 uu = Hv[j + dx];
                    a2p[j] = pkfma(u2h(uu.x), w0, a2p[j]);
                    a2p[j] = pkfma(u2h(uu.y), w1, a2p[j]);
                    a2p[j] = pkfma(u2h(uu.z), w2, a2p[j]);
                    a2p[j] = pkfma(u2h(uu.w), w3, a2p[j]);
                }
            }
        }
        {
            const float b2r = __builtin_bit_cast(float, wsh[92]);
            h2 lo = u2h(A0[1]), hi = u2h(A1[1]);   // residual: image row y
            float4 o;
            o.x = (float)lo[0] + (float)a2p[0][0] + (float)a2p[0][1] + b2r;
            o.y = (float)lo[1] + (float)a2p[1][0] + (float)a2p[1][1] + b2r;
            o.z = (float)hi[0] + (float)a2p[2][0] + (float)a2p[2][1] + b2r;
            o.w = (float)hi[1] + (float)a2p[3][0] + (float)a2p[3][1] + b2r;
            *(float4*)(out + (img0 + img) * HW_ + y * 32 + x0) = o;
        }
    }
}

extern "C" void kernel_launch(void* const* d_in, const int* in_sizes, int n_in,
                              void* d_out, int out_size, void* d_ws, size_t ws_size,
                              hipStream_t stream) {
    const float* queries  = (const float*)d_in[0];
    const float* keys     = (const float*)d_in[1];
    const int*   pos      = (const int*)d_in[2];
    const float* rel_bias = (const float*)d_in[3];
    const float* w1       = (const float*)d_in[4];
    const float* b1       = (const float*)d_in[5];
    const float* w2       = (const float*)d_in[6];
    const float* b2       = (const float*)d_in[7];
    float* out = (float*)d_out;

    unsigned*  wpk   = (unsigned*)d_ws;                                  // 4 KiB slot
    _Float16*  keysh = (_Float16*)((char*)d_ws + 4096);                  // 8 MiB
    _Float16*  xmapg = (_Float16*)((char*)d_ws + 4096 + 8388608);        // 32 MiB

    const int n8 = (B_ * HW_ * C_) / 8;  // 524288
    pack_weights<<<dim3(1), dim3(192), 0, stream>>>(w1, b1, w2, b2, wpk);
    cvt_keys_f16<<<dim3(n8 / 256), dim3(256), 0, stream>>>(keys, keysh, n8);
    attn_kernel<<<dim3(B_ * (Q_ / TQA)), dim3(NTA), 0, stream>>>(
        queries, keysh, pos, rel_bias, xmapg);
    conv_kernel<<<dim3((B_ * Q_) / IPB), dim3(BT), 0, stream>>>(xmapg, wpk, out);
}

// Round 20
// 106.183 us; speedup vs baseline: 1.0577x; 1.0237x over previous
//
#include <hip/hip_runtime.h>

typedef _Float16 h2 __attribute__((ext_vector_type(2)));
typedef _Float16 h8 __attribute__((ext_vector_type(8)));
typedef float f32x4 __attribute__((ext_vector_type(4)));

#define B_  16
#define Q_  1024
#define C_  256
#define HW_ 1024
#define TQA 64     // attn queries per block
#define NTA 512
#define QLD 264    // q_lds leading dim (halfwords): 256 + 8 pad
#define BT  256    // conv kernel threads
#define IPB 4      // images per conv block
#define XRB 80     // bytes per padded ximg row (40 halfwords: 32 px + 8 zero pad)
#define XIMGB (34 * XRB)   // 2720 B per padded image (34 rows, zero top/bottom)
#define HRB 576    // bytes per Hb row (36 slots * 16B, zero border)

__device__ __forceinline__ h2 u2h(unsigned u) { return __builtin_bit_cast(h2, u); }
__device__ __forceinline__ unsigned h2u(h2 h) { return __builtin_bit_cast(unsigned, h); }

// packed f16 fma via native v2f16 type (compiler-encoded v_pk_fma_f16)
__device__ __forceinline__ h2 pkfma(h2 a, h2 b, h2 c) {
#if __has_builtin(__builtin_elementwise_fma)
    return __builtin_elementwise_fma(a, b, c);
#else
    return a * b + c;
#endif
}
__device__ __forceinline__ h2 pkmax0(h2 a) {
#if __has_builtin(__builtin_elementwise_max)
    return __builtin_elementwise_max(a, (h2)(_Float16)0.f);
#else
    h2 r;
    r[0] = a[0] > (_Float16)0.f ? a[0] : (_Float16)0.f;
    r[1] = a[1] > (_Float16)0.f ? a[1] : (_Float16)0.f;
    return r;
#endif
}

// ---------- prepass: keys f32 -> f16, plus weight packing in block 0 ----------
// wpk (u32): [56..91] w2s[t9][c2]=(w2[2c2,t9],w2[2c2+1,t9])   [92] b2 (f32 bits)
//            [96..167]  w1 SPLATS: i: tap=i>>3, ch=i&7 -> (w1[ch][tap], same)
//            [168..175] b1 splats: (b1[ch], b1[ch])
__global__ void cvt_keys_f16(const float* __restrict__ src,
                             _Float16* __restrict__ dst, int n8,
                             const float* __restrict__ w1, const float* __restrict__ b1,
                             const float* __restrict__ w2, const float* __restrict__ b2,
                             unsigned* __restrict__ wpk) {
    int i = blockIdx.x * blockDim.x + threadIdx.x;
    if (blockIdx.x == 0) {
        int t = threadIdx.x;
        if (t >= 56 && t < 92) {
            int k = t - 56; int t9 = k >> 2, c2 = k & 3;
            h2 v = {(_Float16)w2[(2 * c2) * 9 + t9], (_Float16)w2[(2 * c2 + 1) * 9 + t9]};
            wpk[t] = h2u(v);
        } else if (t == 92) {
            wpk[t] = __builtin_bit_cast(unsigned, b2[0]);
        } else if (t >= 96 && t < 168) {
            int k = t - 96; int tap = k >> 3, ch = k & 7;
            _Float16 w = (_Float16)w1[ch * 9 + tap];
            h2 v = {w, w};
            wpk[t] = h2u(v);
        } else if (t >= 168 && t < 176) {
            _Float16 b = (_Float16)b1[t - 168];
            h2 v = {b, b};
            wpk[t] = h2u(v);
        }
    }
    if (i >= n8) return;
    const float4* s = (const float4*)src;
    float4 a = s[2 * i], b = s[2 * i + 1];
    h8 v;
    v[0] = (_Float16)a.x; v[1] = (_Float16)a.y; v[2] = (_Float16)a.z; v[3] = (_Float16)a.w;
    v[4] = (_Float16)b.x; v[5] = (_Float16)b.y; v[6] = (_Float16)b.z; v[7] = (_Float16)b.w;
    *(h8*)(dst + (size_t)i * 8) = v;
}

// ---------- kernel A: QK^T (f16 MFMA, TQ=64, 4 MFMA per B-load) + bias + softmax ----------
__global__ __launch_bounds__(NTA, 2) void attn_kernel(
    const float* __restrict__ queries, const _Float16* __restrict__ keysh,
    const int* __restrict__ pos, const float* __restrict__ rel_bias,
    _Float16* __restrict__ xmapg)
{
    __shared__ _Float16 q_lds[TQA * QLD];      // 33.8 KiB
    __shared__ _Float16 bias_lds[63 * 64];     // 8 KiB
    __shared__ float red_max[8][TQA];
    __shared__ float red_sum[8][TQA];
    __shared__ int2  pos_lds[TQA];

    const int tid = threadIdx.x;
    const int bid = blockIdx.x;
    const int swz = (bid & 7) * 32 + (bid >> 3);    // XCD-chunked (256 % 8 == 0)
    const int batch = swz >> 4;
    const int tile  = swz & 15;

    {
        const float4* qsrc = (const float4*)(queries + (size_t)(batch * Q_ + tile * TQA) * C_);
        #pragma unroll
        for (int i = 0; i < 8; ++i) {
            int e4 = i * NTA + tid;                 // 0..4095
            float4 v = qsrc[e4];
            int row = e4 >> 6, col4 = e4 & 63;
            _Float16* d = &q_lds[row * QLD + col4 * 4];
            d[0] = (_Float16)v.x; d[1] = (_Float16)v.y;
            d[2] = (_Float16)v.z; d[3] = (_Float16)v.w;
        }
        for (int idx = tid; idx < 63 * 63; idx += NTA) {
            int r = idx / 63;
            bias_lds[r * 64 + (idx - r * 63)] = (_Float16)rel_bias[idx];
        }
        if (tid < TQA)
            pos_lds[tid] = ((const int2*)pos)[batch * Q_ + tile * TQA + tid];
    }
    __syncthreads();

    const int lane = tid & 63;
    const int wv   = tid >> 6;          // 0..7 -> 128-col slice
    const int kgrp = (lane >> 4) * 8;
    const int l15  = lane & 15;
    const int rowbase = (lane >> 4) << 2;

    f32x4 acc[4][8];
    #pragma unroll
    for (int mt = 0; mt < 4; ++mt)
        #pragma unroll
        for (int f = 0; f < 8; ++f) acc[mt][f] = f32x4{0.f, 0.f, 0.f, 0.f};

    const _Float16* kb = keysh + (size_t)batch * (HW_ * C_)
                       + (size_t)(wv * 128 + l15) * C_ + kgrp;
    #pragma unroll
    for (int ks = 0; ks < 8; ++ks) {
        h8 a[4];
        #pragma unroll
        for (int mt = 0; mt < 4; ++mt)
            a[mt] = *(const h8*)&q_lds[(mt * 16 + l15) * QLD + ks * 32 + kgrp];
        #pragma unroll
        for (int f = 0; f < 8; ++f) {
            h8 bfr = *(const h8*)(kb + f * (16 * C_) + ks * 32);
            #pragma unroll
            for (int mt = 0; mt < 4; ++mt)
                acc[mt][f] = __builtin_amdgcn_mfma_f32_16x16x32_f16(a[mt], bfr, acc[mt][f], 0, 0, 0);
        }
    }
    // C/D: col = wv*128 + f*16 + l15, row = mt*16 + rowbase + r

    int p0r[4][4], p1r[4][4];
    #pragma unroll
    for (int mt = 0; mt < 4; ++mt)
        #pragma unroll
        for (int r = 0; r < 4; ++r) {
            int2 pp = pos_lds[mt * 16 + rowbase + r];
            p0r[mt][r] = pp.x; p1r[mt][r] = pp.y;
        }

    float mrow[4][4];
    #pragma unroll
    for (int mt = 0; mt < 4; ++mt)
        #pragma unroll
        for (int r = 0; r < 4; ++r) mrow[mt][r] = -3e38f;

    #pragma unroll
    for (int f = 0; f < 8; ++f) {
        int col = wv * 128 + f * 16 + l15;
        int hh = col >> 5, ww = col & 31;
        #pragma unroll
        for (int mt = 0; mt < 4; ++mt)
            #pragma unroll
            for (int r = 0; r < 4; ++r) {
                float s = acc[mt][f][r] * 0.0625f
                        + (float)bias_lds[(hh - p0r[mt][r] + 31) * 64 + (ww - p1r[mt][r] + 31)];
                acc[mt][f][r] = s;
                mrow[mt][r] = fmaxf(mrow[mt][r], s);
            }
    }
    #pragma unroll
    for (int mt = 0; mt < 4; ++mt)
        #pragma unroll
        for (int r = 0; r < 4; ++r) {
            float m = mrow[mt][r];
            m = fmaxf(m, __shfl_xor(m, 1, 64));
            m = fmaxf(m, __shfl_xor(m, 2, 64));
            m = fmaxf(m, __shfl_xor(m, 4, 64));
            m = fmaxf(m, __shfl_xor(m, 8, 64));
            mrow[mt][r] = m;
        }
    if (l15 == 0) {
        #pragma unroll
        for (int mt = 0; mt < 4; ++mt)
            #pragma unroll
            for (int r = 0; r < 4; ++r)
                red_max[wv][mt * 16 + rowbase + r] = mrow[mt][r];
    }
    __syncthreads();

    float sm[4][4];
    #pragma unroll
    for (int mt = 0; mt < 4; ++mt)
        #pragma unroll
        for (int r = 0; r < 4; ++r) {
            float m = red_max[0][mt * 16 + rowbase + r];
            #pragma unroll
            for (int w = 1; w < 8; ++w) m = fmaxf(m, red_max[w][mt * 16 + rowbase + r]);
            mrow[mt][r] = m;     // reuse as row max
            sm[mt][r] = 0.f;
        }

    #pragma unroll
    for (int f = 0; f < 8; ++f) {
        #pragma unroll
        for (int mt = 0; mt < 4; ++mt)
            #pragma unroll
            for (int r = 0; r < 4; ++r) {
                float e = __expf(acc[mt][f][r] - mrow[mt][r]);
                acc[mt][f][r] = e;
                sm[mt][r] += e;
            }
    }
    #pragma unroll
    for (int mt = 0; mt < 4; ++mt)
        #pragma unroll
        for (int r = 0; r < 4; ++r) {
            float s = sm[mt][r];
            s += __shfl_xor(s, 1, 64);
            s += __shfl_xor(s, 2, 64);
            s += __shfl_xor(s, 4, 64);
            s += __shfl_xor(s, 8, 64);
            sm[mt][r] = s;
        }
    if (l15 == 0) {
        #pragma unroll
        for (int mt = 0; mt < 4; ++mt)
            #pragma unroll
            for (int r = 0; r < 4; ++r)
                red_sum[wv][mt * 16 + rowbase + r] = sm[mt][r];
    }
    __syncthreads();

    _Float16* xg = xmapg + (size_t)(batch * Q_ + tile * TQA) * HW_;
    #pragma unroll
    for (int mt = 0; mt < 4; ++mt) {
        float sinv[4];
        #pragma unroll
        for (int r = 0; r < 4; ++r) {
            float S = red_sum[0][mt * 16 + rowbase + r];
            #pragma unroll
            for (int w = 1; w < 8; ++w) S += red_sum[w][mt * 16 + rowbase + r];
            sinv[r] = 1.0f / S;
        }
        #pragma unroll
        for (int f = 0; f < 8; ++f) {
            int col = wv * 128 + f * 16 + l15;
            #pragma unroll
            for (int r = 0; r < 4; ++r)
                xg[(size_t)(mt * 16 + rowbase + r) * HW_ + col]
                    = (_Float16)(acc[mt][f][r] * sinv[r]);
        }
    }
}

// ---------- kernel B: conv1+conv2 packed f16, guard-free, fused-p2 conv1 ----------
__global__ __launch_bounds__(BT, 5) void conv_kernel(
    const _Float16* __restrict__ xmapg, const unsigned* __restrict__ wpk,
    float* __restrict__ out)
{
    __shared__ __align__(16) char xall[16 + IPB * XIMGB];   // 10896 B
    __shared__ __align__(16) char Hb[34 * HRB];             // 19584 B
    __shared__ unsigned wsh[176];                           // 704 B

    const int tid = threadIdx.x;
    const int bid = blockIdx.x;
    const int swz = (bid & 7) * 512 + (bid >> 3);    // XCD-chunked (4096 % 8 == 0)
    const size_t img0 = (size_t)swz * IPB;

    // ---- zero-fill pads/borders; barrier BEFORE interior staging ----
    {
        const uint4 z = uint4{0u, 0u, 0u, 0u};
        uint4* xz = (uint4*)xall;
        for (int i = tid; i < (int)sizeof(xall) / 16; i += BT) xz[i] = z;
        uint4* hz = (uint4*)Hb;
        for (int i = tid; i < (int)sizeof(Hb) / 16; i += BT) hz[i] = z;
    }
    if (tid < 176) wsh[tid] = wpk[tid];
    __syncthreads();

    // ---- stage 4 images (rows at r+1, cols 0..31 of 40) ----
    #pragma unroll
    for (int i = 0; i < 2; ++i) {
        int c = i * BT + tid;            // 0..511 : 16B chunks
        int im = c >> 7, cc = c & 127, r = cc >> 2, q = cc & 3;
        uint4 v = *(const uint4*)(xmapg + img0 * HW_ + (size_t)im * HW_ + cc * 8);
        *(uint4*)(xall + 16 + im * XIMGB + (r + 1) * XRB + q * 16) = v;
    }

    // thread -> (y, 4-px x-run)
    const int m4 = tid & 7;
    const int y  = tid >> 3;
    const int x0 = m4 << 2;

    const char* const xrow0 = xall + 16 + y * XRB + x0 * 2;
    char* const hwr = Hb + (y + 1) * HRB + m4 * 16;         // conv1 store base
    const char* const hrd = Hb + y * HRB + m4 * 16;         // conv2 read base

    __syncthreads();   // staging complete

    #pragma unroll 1
    for (int img = 0; img < IPB; ++img) {
        const char* xi = xrow0 + img * XIMGB;

        // --- gather: 9 unguarded loads + 3 alignbit per row (zero pads guard) ---
        unsigned Pm[3], A0[3], Pc[3], A1[3], Pe[3];
        #pragma unroll
        for (int dy = 0; dy < 3; ++dy) {
            unsigned em = *(const unsigned*)(xi + dy * XRB - 4);   // (v-2, v-1)
            uint2 a01   = *(const uint2*)(xi + dy * XRB);          // v0..v3
            unsigned e4 = *(const unsigned*)(xi + dy * XRB + 8);   // (v4, v5)
            A0[dy] = a01.x; A1[dy] = a01.y;
            Pm[dy] = __builtin_amdgcn_alignbit(a01.x, em, 16);     // (v-1, v0)
            Pc[dy] = __builtin_amdgcn_alignbit(a01.y, a01.x, 16);  // (v1, v2)
            Pe[dy] = __builtin_amdgcn_alignbit(e4, a01.y, 16);     // (v3, v4)
        }

        // --- conv1: packed-f16, BOTH px-pair halves per weight load ---
        h2 acc0[8], acc1[8];
        #pragma unroll
        for (int ch = 0; ch < 8; ++ch) {
            h2 b = u2h(wsh[168 + ch]);
            acc0[ch] = b; acc1[ch] = b;
        }
        #pragma unroll
        for (int dy = 0; dy < 3; ++dy) {
            #pragma unroll
            for (int ch = 0; ch < 8; ++ch) {
                const h2 wt0 = u2h(wsh[96 + (dy * 3 + 0) * 8 + ch]);
                const h2 wt1 = u2h(wsh[96 + (dy * 3 + 1) * 8 + ch]);
                const h2 wt2 = u2h(wsh[96 + (dy * 3 + 2) * 8 + ch]);
                acc0[ch] = pkfma(u2h(Pm[dy]), wt0, acc0[ch]);
                acc0[ch] = pkfma(u2h(A0[dy]), wt1, acc0[ch]);
                acc0[ch] = pkfma(u2h(Pc[dy]), wt2, acc0[ch]);
                acc1[ch] = pkfma(u2h(Pc[dy]), wt0, acc1[ch]);
                acc1[ch] = pkfma(u2h(A1[dy]), wt1, acc1[ch]);
                acc1[ch] = pkfma(u2h(Pe[dy]), wt2, acc1[ch]);
            }
        }
        unsigned hvw[4][4];   // [px][chpair word]
        #pragma unroll
        for (int w = 0; w < 4; ++w) {
            unsigned a0 = h2u(pkmax0(acc0[2 * w]));
            unsigned b0 = h2u(pkmax0(acc0[2 * w + 1]));
            hvw[0][w] = (a0 & 0xffffu) | (b0 << 16);
            hvw[1][w] = (a0 >> 16) | (b0 & 0xffff0000u);
            unsigned a1 = h2u(pkmax0(acc1[2 * w]));
            unsigned b1w = h2u(pkmax0(acc1[2 * w + 1]));
            hvw[2][w] = (a1 & 0xffffu) | (b1w << 16);
            hvw[3][w] = (a1 >> 16) | (b1w & 0xffff0000u);
        }

        __syncthreads();   // previous image's conv2 readers done with Hb

        // store (bordered slots: cp=x0+j+1 -> (cp&3)*9+(cp>>2))
        {
            *(uint4*)(hwr + 144) = uint4{hvw[0][0], hvw[0][1], hvw[0][2], hvw[0][3]};
            *(uint4*)(hwr + 288) = uint4{hvw[1][0], hvw[1][1], hvw[1][2], hvw[1][3]};
            *(uint4*)(hwr + 432) = uint4{hvw[2][0], hvw[2][1], hvw[2][2], hvw[2][3]};
            *(uint4*)(hwr + 16)  = uint4{hvw[3][0], hvw[3][1], hvw[3][2], hvw[3][3]};
        }
        __syncthreads();   // Hb ready

        // --- conv2: packed-f16 ch-pair accum, unguarded reads (zero border) ---
        h2 a2p[4];
        #pragma unroll
        for (int j = 0; j < 4; ++j) a2p[j] = u2h(0u);
        #pragma unroll
        for (int dy = 0; dy < 3; ++dy) {
            const char* rb = hrd + dy * HRB;
            uint4 Hv[6];
            Hv[0] = *(const uint4*)(rb + 0);     // c = x0-1
            Hv[1] = *(const uint4*)(rb + 144);   // c = x0
            Hv[2] = *(const uint4*)(rb + 288);   // c = x0+1
            Hv[3] = *(const uint4*)(rb + 432);   // c = x0+2
            Hv[4] = *(const uint4*)(rb + 16);    // c = x0+3
            Hv[5] = *(const uint4*)(rb + 160);   // c = x0+4
            #pragma unroll
            for (int dx = 0; dx < 3; ++dx) {
                const int tt = dy * 3 + dx;
                const h2 w0 = u2h(wsh[56 + tt * 4 + 0]);
                const h2 w1 = u2h(wsh[56 + tt * 4 + 1]);
                const h2 w2 = u2h(wsh[56 + tt * 4 + 2]);
                const h2 w3 = u2h(wsh[56 + tt * 4 + 3]);
                #pragma unroll
                for (int j = 0; j < 4; ++j) {
                    const uint4 uu = Hv[j + dx];
                    a2p[j] = pkfma(u2h(uu.x), w0, a2p[j]);
                    a2p[j] = pkfma(u2h(uu.y), w1, a2p[j]);
                    a2p[j] = pkfma(u2h(uu.z), w2, a2p[j]);
                    a2p[j] = pkfma(u2h(uu.w), w3, a2p[j]);
                }
            }
        }
        {
            const float b2r = __builtin_bit_cast(float, wsh[92]);
            h2 lo = u2h(A0[1]), hi = u2h(A1[1]);   // residual: image row y
            float4 o;
            o.x = (float)lo[0] + (float)a2p[0][0] + (float)a2p[0][1] + b2r;
            o.y = (float)lo[1] + (float)a2p[1][0] + (float)a2p[1][1] + b2r;
            o.z = (float)hi[0] + (float)a2p[2][0] + (float)a2p[2][1] + b2r;
            o.w = (float)hi[1] + (float)a2p[3][0] + (float)a2p[3][1] + b2r;
            *(float4*)(out + (img0 + img) * HW_ + y * 32 + x0) = o;
        }
    }
}

extern "C" void kernel_launch(void* const* d_in, const int* in_sizes, int n_in,
                              void* d_out, int out_size, void* d_ws, size_t ws_size,
                              hipStream_t stream) {
    const float* queries  = (const float*)d_in[0];
    const float* keys     = (const float*)d_in[1];
    const int*   pos      = (const int*)d_in[2];
    const float* rel_bias = (const float*)d_in[3];
    const float* w1       = (const float*)d_in[4];
    const float* b1       = (const float*)d_in[5];
    const float* w2       = (const float*)d_in[6];
    const float* b2       = (const float*)d_in[7];
    float* out = (float*)d_out;

    unsigned*  wpk   = (unsigned*)d_ws;                                  // 4 KiB slot
    _Float16*  keysh = (_Float16*)((char*)d_ws + 4096);                  // 8 MiB
    _Float16*  xmapg = (_Float16*)((char*)d_ws + 4096 + 8388608);        // 32 MiB

    const int n8 = (B_ * HW_ * C_) / 8;  // 524288
    cvt_keys_f16<<<dim3(n8 / 256), dim3(256), 0, stream>>>(keys, keysh, n8,
                                                           w1, b1, w2, b2, wpk);
    attn_kernel<<<dim3(B_ * (Q_ / TQA)), dim3(NTA), 0, stream>>>(
        queries, keysh, pos, rel_bias, xmapg);
    conv_kernel<<<dim3((B_ * Q_) / IPB), dim3(BT), 0, stream>>>(xmapg, wpk, out);
}

// Round 21
// 99.098 us; speedup vs baseline: 1.1333x; 1.0715x over previous
//
#include <hip/hip_runtime.h>

typedef _Float16 h2 __attribute__((ext_vector_type(2)));
typedef _Float16 h8 __attribute__((ext_vector_type(8)));
typedef float f32x4 __attribute__((ext_vector_type(4)));

#define B_  16
#define Q_  1024
#define C_  256
#define HW_ 1024
#define TQA 64     // attn queries per block
#define NTA 512
#define QLD 264    // q_lds leading dim (halfwords): 256 + 8 pad
#define BT  256    // conv kernel threads
#define IPB 4      // images per conv block
#define XRB 80     // bytes per padded ximg row (40 halfwords: 32 px + 8 zero pad)
#define XIMGB (34 * XRB)   // 2720 B per padded image (34 rows, zero top/bottom)
#define HRB 576    // bytes per Hb row (36 slots * 16B, zero border)

__device__ __forceinline__ h2 u2h(unsigned u) { return __builtin_bit_cast(h2, u); }
__device__ __forceinline__ unsigned h2u(h2 h) { return __builtin_bit_cast(unsigned, h); }

// packed f16 fma via native v2f16 type (compiler-encoded v_pk_fma_f16)
__device__ __forceinline__ h2 pkfma(h2 a, h2 b, h2 c) {
#if __has_builtin(__builtin_elementwise_fma)
    return __builtin_elementwise_fma(a, b, c);
#else
    return a * b + c;
#endif
}
__device__ __forceinline__ h2 pkmax0(h2 a) {
#if __has_builtin(__builtin_elementwise_max)
    return __builtin_elementwise_max(a, (h2)(_Float16)0.f);
#else
    h2 r;
    r[0] = a[0] > (_Float16)0.f ? a[0] : (_Float16)0.f;
    r[1] = a[1] > (_Float16)0.f ? a[1] : (_Float16)0.f;
    return r;
#endif
}

// ---------- prepass: keys f32 -> f16, plus weight packing in block 0 ----------
// wpk (u32): [56..91] w2s[t9][c2]=(w2[2c2,t9],w2[2c2+1,t9])   [92] b2 (f32 bits)
//            [96..167]  w1 SPLATS: tap=i>>3, ch=i&7 -> (w1[ch][tap], same)
//            [168..175] b1 splats: (b1[ch], b1[ch])
__global__ void cvt_keys_f16(const float* __restrict__ src,
                             _Float16* __restrict__ dst, int n8,
                             const float* __restrict__ w1, const float* __restrict__ b1,
                             const float* __restrict__ w2, const float* __restrict__ b2,
                             unsigned* __restrict__ wpk) {
    int i = blockIdx.x * blockDim.x + threadIdx.x;
    if (blockIdx.x == 0) {
        int t = threadIdx.x;
        if (t >= 56 && t < 92) {
            int k = t - 56; int t9 = k >> 2, c2 = k & 3;
            h2 v = {(_Float16)w2[(2 * c2) * 9 + t9], (_Float16)w2[(2 * c2 + 1) * 9 + t9]};
            wpk[t] = h2u(v);
        } else if (t == 92) {
            wpk[t] = __builtin_bit_cast(unsigned, b2[0]);
        } else if (t >= 96 && t < 168) {
            int k = t - 96; int tap = k >> 3, ch = k & 7;
            _Float16 w = (_Float16)w1[ch * 9 + tap];
            h2 v = {w, w};
            wpk[t] = h2u(v);
        } else if (t >= 168 && t < 176) {
            _Float16 b = (_Float16)b1[t - 168];
            h2 v = {b, b};
            wpk[t] = h2u(v);
        }
    }
    if (i >= n8) return;
    const float4* s = (const float4*)src;
    float4 a = s[2 * i], b = s[2 * i + 1];
    h8 v;
    v[0] = (_Float16)a.x; v[1] = (_Float16)a.y; v[2] = (_Float16)a.z; v[3] = (_Float16)a.w;
    v[4] = (_Float16)b.x; v[5] = (_Float16)b.y; v[6] = (_Float16)b.z; v[7] = (_Float16)b.w;
    *(h8*)(dst + (size_t)i * 8) = v;
}

// ---------- kernel A: QK^T (f16 MFMA, TQ=64, 4 MFMA per B-load) + bias + softmax ----------
__global__ __launch_bounds__(NTA, 2) void attn_kernel(
    const float* __restrict__ queries, const _Float16* __restrict__ keysh,
    const int* __restrict__ pos, const float* __restrict__ rel_bias,
    _Float16* __restrict__ xmapg)
{
    __shared__ _Float16 q_lds[TQA * QLD];      // 33.8 KiB
    __shared__ _Float16 bias_lds[63 * 64];     // 8 KiB
    __shared__ float red_max[8][TQA];
    __shared__ float red_sum[8][TQA];
    __shared__ int2  pos_lds[TQA];

    const int tid = threadIdx.x;
    const int bid = blockIdx.x;
    const int swz = (bid & 7) * 32 + (bid >> 3);    // XCD-chunked (256 % 8 == 0)
    const int batch = swz >> 4;
    const int tile  = swz & 15;

    {
        const float4* qsrc = (const float4*)(queries + (size_t)(batch * Q_ + tile * TQA) * C_);
        #pragma unroll
        for (int i = 0; i < 8; ++i) {
            int e4 = i * NTA + tid;                 // 0..4095
            float4 v = qsrc[e4];
            int row = e4 >> 6, col4 = e4 & 63;
            _Float16* d = &q_lds[row * QLD + col4 * 4];
            d[0] = (_Float16)v.x; d[1] = (_Float16)v.y;
            d[2] = (_Float16)v.z; d[3] = (_Float16)v.w;
        }
        for (int idx = tid; idx < 63 * 63; idx += NTA) {
            int r = idx / 63;
            bias_lds[r * 64 + (idx - r * 63)] = (_Float16)rel_bias[idx];
        }
        if (tid < TQA)
            pos_lds[tid] = ((const int2*)pos)[batch * Q_ + tile * TQA + tid];
    }
    __syncthreads();

    const int lane = tid & 63;
    const int wv   = tid >> 6;          // 0..7 -> 128-col slice
    const int kgrp = (lane >> 4) * 8;
    const int l15  = lane & 15;
    const int rowbase = (lane >> 4) << 2;

    f32x4 acc[4][8];
    #pragma unroll
    for (int mt = 0; mt < 4; ++mt)
        #pragma unroll
        for (int f = 0; f < 8; ++f) acc[mt][f] = f32x4{0.f, 0.f, 0.f, 0.f};

    const _Float16* kb = keysh + (size_t)batch * (HW_ * C_)
                       + (size_t)(wv * 128 + l15) * C_ + kgrp;
    #pragma unroll
    for (int ks = 0; ks < 8; ++ks) {
        h8 a[4];
        #pragma unroll
        for (int mt = 0; mt < 4; ++mt)
            a[mt] = *(const h8*)&q_lds[(mt * 16 + l15) * QLD + ks * 32 + kgrp];
        #pragma unroll
        for (int f = 0; f < 8; ++f) {
            h8 bfr = *(const h8*)(kb + f * (16 * C_) + ks * 32);
            #pragma unroll
            for (int mt = 0; mt < 4; ++mt)
                acc[mt][f] = __builtin_amdgcn_mfma_f32_16x16x32_f16(a[mt], bfr, acc[mt][f], 0, 0, 0);
        }
    }
    // C/D: col = wv*128 + f*16 + l15, row = mt*16 + rowbase + r

    int p0r[4][4], p1r[4][4];
    #pragma unroll
    for (int mt = 0; mt < 4; ++mt)
        #pragma unroll
        for (int r = 0; r < 4; ++r) {
            int2 pp = pos_lds[mt * 16 + rowbase + r];
            p0r[mt][r] = pp.x; p1r[mt][r] = pp.y;
        }

    float mrow[4][4];
    #pragma unroll
    for (int mt = 0; mt < 4; ++mt)
        #pragma unroll
        for (int r = 0; r < 4; ++r) mrow[mt][r] = -3e38f;

    #pragma unroll
    for (int f = 0; f < 8; ++f) {
        int col = wv * 128 + f * 16 + l15;
        int hh = col >> 5, ww = col & 31;
        #pragma unroll
        for (int mt = 0; mt < 4; ++mt)
            #pragma unroll
            for (int r = 0; r < 4; ++r) {
                float s = acc[mt][f][r] * 0.0625f
                        + (float)bias_lds[(hh - p0r[mt][r] + 31) * 64 + (ww - p1r[mt][r] + 31)];
                acc[mt][f][r] = s;
                mrow[mt][r] = fmaxf(mrow[mt][r], s);
            }
    }
    #pragma unroll
    for (int mt = 0; mt < 4; ++mt)
        #pragma unroll
        for (int r = 0; r < 4; ++r) {
            float m = mrow[mt][r];
            m = fmaxf(m, __shfl_xor(m, 1, 64));
            m = fmaxf(m, __shfl_xor(m, 2, 64));
            m = fmaxf(m, __shfl_xor(m, 4, 64));
            m = fmaxf(m, __shfl_xor(m, 8, 64));
            mrow[mt][r] = m;
        }
    if (l15 == 0) {
        #pragma unroll
        for (int mt = 0; mt < 4; ++mt)
            #pragma unroll
            for (int r = 0; r < 4; ++r)
                red_max[wv][mt * 16 + rowbase + r] = mrow[mt][r];
    }
    __syncthreads();

    float sm[4][4];
    #pragma unroll
    for (int mt = 0; mt < 4; ++mt)
        #pragma unroll
        for (int r = 0; r < 4; ++r) {
            float m = red_max[0][mt * 16 + rowbase + r];
            #pragma unroll
            for (int w = 1; w < 8; ++w) m = fmaxf(m, red_max[w][mt * 16 + rowbase + r]);
            mrow[mt][r] = m;     // reuse as row max
            sm[mt][r] = 0.f;
        }

    #pragma unroll
    for (int f = 0; f < 8; ++f) {
        #pragma unroll
        for (int mt = 0; mt < 4; ++mt)
            #pragma unroll
            for (int r = 0; r < 4; ++r) {
                float e = __expf(acc[mt][f][r] - mrow[mt][r]);
                acc[mt][f][r] = e;
                sm[mt][r] += e;
            }
    }
    #pragma unroll
    for (int mt = 0; mt < 4; ++mt)
        #pragma unroll
        for (int r = 0; r < 4; ++r) {
            float s = sm[mt][r];
            s += __shfl_xor(s, 1, 64);
            s += __shfl_xor(s, 2, 64);
            s += __shfl_xor(s, 4, 64);
            s += __shfl_xor(s, 8, 64);
            sm[mt][r] = s;
        }
    if (l15 == 0) {
        #pragma unroll
        for (int mt = 0; mt < 4; ++mt)
            #pragma unroll
            for (int r = 0; r < 4; ++r)
                red_sum[wv][mt * 16 + rowbase + r] = sm[mt][r];
    }
    __syncthreads();

    _Float16* xg = xmapg + (size_t)(batch * Q_ + tile * TQA) * HW_;
    #pragma unroll
    for (int mt = 0; mt < 4; ++mt) {
        float sinv[4];
        #pragma unroll
        for (int r = 0; r < 4; ++r) {
            float S = red_sum[0][mt * 16 + rowbase + r];
            #pragma unroll
            for (int w = 1; w < 8; ++w) S += red_sum[w][mt * 16 + rowbase + r];
            sinv[r] = 1.0f / S;
        }
        #pragma unroll
        for (int f = 0; f < 8; ++f) {
            int col = wv * 128 + f * 16 + l15;
            #pragma unroll
            for (int r = 0; r < 4; ++r)
                xg[(size_t)(mt * 16 + rowbase + r) * HW_ + col]
                    = (_Float16)(acc[mt][f][r] * sinv[r]);
        }
    }
}

// ---------- kernel B: conv1+conv2 packed f16, guard-free, reduced LDS issue ----------
__global__ __launch_bounds__(BT, 4) void conv_kernel(
    const _Float16* __restrict__ xmapg, const unsigned* __restrict__ wpk,
    float* __restrict__ out)
{
    __shared__ __align__(16) char xall[16 + IPB * XIMGB];   // 10896 B
    __shared__ __align__(16) char Hb[34 * HRB];             // 19584 B
    __shared__ unsigned wsh[176];                           // 704 B

    const int tid = threadIdx.x;
    const int bid = blockIdx.x;
    const int swz = (bid & 7) * 512 + (bid >> 3);    // XCD-chunked (4096 % 8 == 0)
    const size_t img0 = (size_t)swz * IPB;

    // ---- zero-fill pads/borders; barrier BEFORE interior staging ----
    {
        const uint4 z = uint4{0u, 0u, 0u, 0u};
        uint4* xz = (uint4*)xall;
        for (int i = tid; i < (int)sizeof(xall) / 16; i += BT) xz[i] = z;
        uint4* hz = (uint4*)Hb;
        for (int i = tid; i < (int)sizeof(Hb) / 16; i += BT) hz[i] = z;
    }
    if (tid < 176) wsh[tid] = wpk[tid];
    __syncthreads();

    // ---- stage 4 images (rows at r+1, cols 0..31 of 40) ----
    #pragma unroll
    for (int i = 0; i < 2; ++i) {
        int c = i * BT + tid;            // 0..511 : 16B chunks
        int im = c >> 7, cc = c & 127, r = cc >> 2, q = cc & 3;
        uint4 v = *(const uint4*)(xmapg + img0 * HW_ + (size_t)im * HW_ + cc * 8);
        *(uint4*)(xall + 16 + im * XIMGB + (r + 1) * XRB + q * 16) = v;
    }

    // thread -> (y, 4-px x-run)
    const int m4 = tid & 7;
    const int y  = tid >> 3;
    const int x0 = m4 << 2;

    const char* const xrow0 = xall + 16 + y * XRB + x0 * 2;
    char* const hwr = Hb + (y + 1) * HRB + m4 * 16;         // conv1 store base
    const char* const hrd = Hb + y * HRB + m4 * 16;         // conv2 read base

    __syncthreads();   // staging + wsh complete

    // ---- conv2 weights + b2 hoisted to registers (9 b128 reads, once) ----
    h2 w2r[9][4];
    #pragma unroll
    for (int t = 0; t < 9; ++t) {
        uint4 w = *(const uint4*)&wsh[56 + t * 4];
        w2r[t][0] = u2h(w.x); w2r[t][1] = u2h(w.y);
        w2r[t][2] = u2h(w.z); w2r[t][3] = u2h(w.w);
    }
    const float b2r = __builtin_bit_cast(float, wsh[92]);

    #pragma unroll 1
    for (int img = 0; img < IPB; ++img) {
        const char* xi = xrow0 + img * XIMGB;

        // --- gather: 9 unguarded loads + 3 alignbit per row (zero pads guard) ---
        unsigned Pm[3], A0[3], Pc[3], A1[3], Pe[3];
        #pragma unroll
        for (int dy = 0; dy < 3; ++dy) {
            unsigned em = *(const unsigned*)(xi + dy * XRB - 4);   // (v-2, v-1)
            uint2 a01   = *(const uint2*)(xi + dy * XRB);          // v0..v3
            unsigned e4 = *(const unsigned*)(xi + dy * XRB + 8);   // (v4, v5)
            A0[dy] = a01.x; A1[dy] = a01.y;
            Pm[dy] = __builtin_amdgcn_alignbit(a01.x, em, 16);     // (v-1, v0)
            Pc[dy] = __builtin_amdgcn_alignbit(a01.y, a01.x, 16);  // (v1, v2)
            Pe[dy] = __builtin_amdgcn_alignbit(e4, a01.y, 16);     // (v3, v4)
        }

        // --- conv1: packed-f16, weights via 6 b128 reads per dy ---
        h2 acc0[8], acc1[8];
        #pragma unroll
        for (int ch = 0; ch < 8; ++ch) {
            h2 b = u2h(wsh[168 + ch]);
            acc0[ch] = b; acc1[ch] = b;
        }
        #pragma unroll
        for (int dy = 0; dy < 3; ++dy) {
            uint4 W[6];   // taps dy*3..dy*3+2, ch 0..7 (24 h2 words)
            #pragma unroll
            for (int q = 0; q < 6; ++q)
                W[q] = *(const uint4*)&wsh[96 + dy * 24 + q * 4];
            const unsigned* Wu = (const unsigned*)W;
            #pragma unroll
            for (int ch = 0; ch < 8; ++ch) {
                const h2 wt0 = u2h(Wu[0 + ch]);
                const h2 wt1 = u2h(Wu[8 + ch]);
                const h2 wt2 = u2h(Wu[16 + ch]);
                acc0[ch] = pkfma(u2h(Pm[dy]), wt0, acc0[ch]);
                acc0[ch] = pkfma(u2h(A0[dy]), wt1, acc0[ch]);
                acc0[ch] = pkfma(u2h(Pc[dy]), wt2, acc0[ch]);
                acc1[ch] = pkfma(u2h(Pc[dy]), wt0, acc1[ch]);
                acc1[ch] = pkfma(u2h(A1[dy]), wt1, acc1[ch]);
                acc1[ch] = pkfma(u2h(Pe[dy]), wt2, acc1[ch]);
            }
        }
        uint4 hvq[4];   // [px] channel words (transposed)
        #pragma unroll
        for (int w = 0; w < 4; ++w) {
            unsigned a0 = h2u(pkmax0(acc0[2 * w]));
            unsigned b0 = h2u(pkmax0(acc0[2 * w + 1]));
            ((unsigned*)&hvq[0])[w] = (a0 & 0xffffu) | (b0 << 16);
            ((unsigned*)&hvq[1])[w] = (a0 >> 16) | (b0 & 0xffff0000u);
            unsigned a1 = h2u(pkmax0(acc1[2 * w]));
            unsigned b1w = h2u(pkmax0(acc1[2 * w + 1]));
            ((unsigned*)&hvq[2])[w] = (a1 & 0xffffu) | (b1w << 16);
            ((unsigned*)&hvq[3])[w] = (a1 >> 16) | (b1w & 0xffff0000u);
        }

        __syncthreads();   // previous image's conv2 readers done with Hb

        // store (bordered slots: cp=x0+j+1 -> (cp&3)*9+(cp>>2))
        {
            *(uint4*)(hwr + 144) = hvq[0];
            *(uint4*)(hwr + 288) = hvq[1];
            *(uint4*)(hwr + 432) = hvq[2];
            *(uint4*)(hwr + 16)  = hvq[3];
        }
        __syncthreads();   // Hb ready

        // --- conv2: packed-f16 ch-pair accum; dy=1 center slots from registers ---
        h2 a2p[4];
        #pragma unroll
        for (int j = 0; j < 4; ++j) a2p[j] = u2h(0u);
        #pragma unroll
        for (int dy = 0; dy < 3; ++dy) {
            const char* rb = hrd + dy * HRB;
            uint4 Hv[6];
            Hv[0] = *(const uint4*)(rb + 0);     // c = x0-1
            if (dy == 1) {
                Hv[1] = hvq[0]; Hv[2] = hvq[1];  // own just-stored values
                Hv[3] = hvq[2]; Hv[4] = hvq[3];
            } else {
                Hv[1] = *(const uint4*)(rb + 144);
                Hv[2] = *(const uint4*)(rb + 288);
                Hv[3] = *(const uint4*)(rb + 432);
                Hv[4] = *(const uint4*)(rb + 16);
            }
            Hv[5] = *(const uint4*)(rb + 160);   // c = x0+4
            #pragma unroll
            for (int dx = 0; dx < 3; ++dx) {
                const int tt = dy * 3 + dx;
                #pragma unroll
                for (int j = 0; j < 4; ++j) {
                    const uint4 uu = Hv[j + dx];
                    a2p[j] = pkfma(u2h(uu.x), w2r[tt][0], a2p[j]);
                    a2p[j] = pkfma(u2h(uu.y), w2r[tt][1], a2p[j]);
                    a2p[j] = pkfma(u2h(uu.z), w2r[tt][2], a2p[j]);
                    a2p[j] = pkfma(u2h(uu.w), w2r[tt][3], a2p[j]);
                }
            }
        }
        {
            h2 lo = u2h(A0[1]), hi = u2h(A1[1]);   // residual: image row y
            float4 o;
            o.x = (float)lo[0] + (float)a2p[0][0] + (float)a2p[0][1] + b2r;
            o.y = (float)lo[1] + (float)a2p[1][0] + (float)a2p[1][1] + b2r;
            o.z = (float)hi[0] + (float)a2p[2][0] + (float)a2p[2][1] + b2r;
            o.w = (float)hi[1] + (float)a2p[3][0] + (float)a2p[3][1] + b2r;
            *(float4*)(out + (img0 + img) * HW_ + y * 32 + x0) = o;
        }
    }
}

extern "C" void kernel_launch(void* const* d_in, const int* in_sizes, int n_in,
                              void* d_out, int out_size, void* d_ws, size_t ws_size,
                              hipStream_t stream) {
    const float* queries  = (const float*)d_in[0];
    const float* keys     = (const float*)d_in[1];
    const int*   pos      = (const int*)d_in[2];
    const float* rel_bias = (const float*)d_in[3];
    const float* w1       = (const float*)d_in[4];
    const float* b1       = (const float*)d_in[5];
    const float* w2       = (const float*)d_in[6];
    const float* b2       = (const float*)d_in[7];
    float* out = (float*)d_out;

    unsigned*  wpk   = (unsigned*)d_ws;                                  // 4 KiB slot
    _Float16*  keysh = (_Float16*)((char*)d_ws + 4096);                  // 8 MiB
    _Float16*  xmapg = (_Float16*)((char*)d_ws + 4096 + 8388608);        // 32 MiB

    const int n8 = (B_ * HW_ * C_) / 8;  // 524288
    cvt_keys_f16<<<dim3(n8 / 256), dim3(256), 0, stream>>>(keys, keysh, n8,
                                                           w1, b1, w2, b2, wpk);
    attn_kernel<<<dim3(B_ * (Q_ / TQA)), dim3(NTA), 0, stream>>>(
        queries, keysh, pos, rel_bias, xmapg);
    conv_kernel<<<dim3((B_ * Q_) / IPB), dim3(BT), 0, stream>>>(xmapg, wpk, out);
}